// Round 14
// baseline (446.283 us; speedup 1.0000x reference)
//
#include <hip/hip_runtime.h>
#include <stdint.h>

typedef __attribute__((ext_vector_type(8))) short bf16x8;
typedef __attribute__((ext_vector_type(4))) float f32x4;

#define LOG2E 1.4426950408889634f

__device__ __forceinline__ unsigned short f2bf(float f){
  union { float f; unsigned u; } v; v.f = f;
  return (unsigned short)((v.u + 0x7fffu + ((v.u >> 16) & 1u)) >> 16);
}
__device__ __forceinline__ float bf2f(unsigned short h){
  union { unsigned u; float f; } v; v.u = ((unsigned)h) << 16; return v.f;
}
__device__ __forceinline__ float fast_exp2(float x){
  float r; asm("v_exp_f32 %0, %1" : "=v"(r) : "v"(x)); return r;
}
__device__ __forceinline__ unsigned cvt_pk_bf16(float lo, float hi){
  unsigned r; asm("v_cvt_pk_bf16_f32 %0, %1, %2" : "=v"(r) : "v"(lo), "v"(hi)); return r;
}
__device__ __forceinline__ void gload16(const void* g, void* lds){
  __builtin_amdgcn_global_load_lds((const __attribute__((address_space(1))) unsigned int*)g,
                                   (__attribute__((address_space(3))) unsigned int*)lds,
                                   16, 0, 0);
}
#define MFMA(a,b,c) __builtin_amdgcn_mfma_f32_16x16x32_bf16((a),(b),(c),0,0,0)

// B=8, H=W=64, N=4096, C=512, nh=8, hd=64

__global__ void k_conv_x(const float* __restrict__ x, unsigned short* __restrict__ xb, int n){
  int i = (blockIdx.x*256 + threadIdx.x)*8;
  if (i >= n) return;
  float4 a = *(const float4*)(x+i);
  float4 b = *(const float4*)(x+i+4);
  *(ushort4*)(xb+i)   = make_ushort4(f2bf(a.x), f2bf(a.y), f2bf(a.z), f2bf(a.w));
  *(ushort4*)(xb+i+4) = make_ushort4(f2bf(b.x), f2bf(b.y), f2bf(b.z), f2bf(b.w));
}

// Merged prep: weights + bias tables (tables pre-scaled by log2(e) for base-2 softmax).
__global__ void k_prep(const float* __restrict__ Wq, const float* __restrict__ Wkv,
                       const float* __restrict__ Wp,
                       const float* t1,const float* t2,const float* t3,const float* t4,
                       const float* t5,const float* t6,const float* t7,
                       unsigned short* __restrict__ wqkv, unsigned short* __restrict__ wsp,
                       float* __restrict__ b64, float* __restrict__ b256){
  int i = blockIdx.x*256 + threadIdx.x;
  int stride = gridDim.x*256;
  for (int e = i; e < 1536*512; e += stride){
    int r = e >> 9;
    wqkv[e] = f2bf(r < 512 ? Wq[e] : Wkv[e - 512*512]);
  }
  for (int e = i; e < 512*512; e += stride)
    wsp[e] = f2bf(Wp[e]);
  for (int e = i; e < 5*4096; e += stride){
    int hh = e >> 12;
    int q = (e >> 6) & 63, kk = e & 63;
    float v;
    if (hh < 2){                       // p=4: unit token t = r*16 + i*4 + c, strip mask
      const float* tb = hh ? t2 : t1;
      int r1=q>>4, i1=(q>>2)&3, c1=q&3;
      int r2=kk>>4, i2=(kk>>2)&3, c2=kk&3;
      v = (i1==i2) ? tb[(r1-r2+3)*7 + (c1-c2+3)] : -1e30f;
    } else {                           // p=8: t = r*8 + c
      const float* tb = (hh==2)?t3:((hh==3)?t4:t5);
      int r1=q>>3, c1=q&7, r2=kk>>3, c2=kk&7;
      v = tb[(r1-r2+7)*15 + (c1-c2+7)];
    }
    b64[e] = v * LOG2E;
  }
  for (int e = i; e < 2*65536; e += stride){
    int hh = e >> 16; int q = (e >> 8) & 255, kk = e & 255;
    const float* tb = hh ? t7 : t6;
    int r1=q>>4, c1=q&15, r2=kk>>4, c2=kk&15;
    b256[e] = tb[(r1-r2+15)*31 + (c1-c2+15)] * LOG2E;
  }
}

// ---------- GEMM (validated), K=512 for both uses ----------
template<int EPI>
__global__ __launch_bounds__(256, 2)
void k_gemm(const unsigned short* __restrict__ A, const unsigned short* __restrict__ Bw,
            int M,
            unsigned short* __restrict__ oq, unsigned short* __restrict__ ok,
            unsigned short* __restrict__ ovt,
            float* __restrict__ of, const float* __restrict__ bias)
{
  __shared__ unsigned short As[128*64];
  __shared__ unsigned short Bs[128*64];
  const int t = threadIdx.x, l = t & 63, w = t >> 6;
  const int mt = M >> 7;
  const int bm = blockIdx.x % mt, bn = blockIdx.x / mt;
  const int m0 = bm << 7, n0 = bn << 7;
  const int wr = w >> 1, wc = w & 1;
  const int lr = l & 15, lg = l >> 4;
  f32x4 acc[4][4] = {};

  for (int k0 = 0; k0 < 512; k0 += 64){
    #pragma unroll
    for (int i = 0; i < 4; i++){
      int rowb = i*32 + w*8;
      int row  = rowb + (l >> 3);
      int sc   = (((l & 7) ^ (row & 7)) << 3);
      gload16(A  + (size_t)(m0 + row)*512 + k0 + sc, &As[rowb*64]);
      gload16(Bw + (size_t)(n0 + row)*512 + k0 + sc, &Bs[rowb*64]);
    }
    __syncthreads();
    #pragma unroll
    for (int kt = 0; kt < 2; kt++){
      bf16x8 af[4], bfr[4];
      #pragma unroll
      for (int mi = 0; mi < 4; mi++){
        int row = wr*64 + mi*16 + lr;
        int cb  = (kt*64 + lg*16) ^ ((row & 7) << 4);
        af[mi] = *(const bf16x8*)((const char*)As + row*128 + cb);
      }
      #pragma unroll
      for (int ni = 0; ni < 4; ni++){
        int row = wc*64 + ni*16 + lr;
        int cb  = (kt*64 + lg*16) ^ ((row & 7) << 4);
        bfr[ni] = *(const bf16x8*)((const char*)Bs + row*128 + cb);
      }
      #pragma unroll
      for (int mi = 0; mi < 4; mi++)
        #pragma unroll
        for (int ni = 0; ni < 4; ni++)
          acc[mi][ni] = MFMA(af[mi], bfr[ni], acc[mi][ni]);
    }
    __syncthreads();
  }

  #pragma unroll
  for (int mi = 0; mi < 4; mi++){
    #pragma unroll
    for (int ni = 0; ni < 4; ni++){
      int m = m0 + wr*64 + mi*16 + lg*4;
      int o = n0 + wc*64 + ni*16 + lr;
      if (EPI == 0){
        int which = o >> 9, oo = o & 511, h = oo >> 6, d = oo & 63;
        int b_ = m >> 12, n_ = m & 4095;
        if (which == 2){
          *(ushort4*)(ovt + ((((size_t)b_*8 + h)*64 + d) << 12) + n_) =
            make_ushort4(f2bf(acc[mi][ni][0]), f2bf(acc[mi][ni][1]),
                         f2bf(acc[mi][ni][2]), f2bf(acc[mi][ni][3]));
        } else {
          unsigned short* dst = (which == 0) ? oq : ok;
          size_t base = (((size_t)(b_*8 + h)) << 18) + ((size_t)n_ << 6) + d;
          #pragma unroll
          for (int r = 0; r < 4; r++)
            dst[base + (size_t)r*64] = f2bf(acc[mi][ni][r]);
        }
      } else {
        float bv = bias[o];
        #pragma unroll
        for (int r = 0; r < 4; r++)
          of[(size_t)(m + r)*512 + o] = acc[mi][ni][r] + bv;
      }
    }
  }
}

// ---------- flash (h0 + h6/7): 16-row waves for <=64 VGPR -> 8 waves/SIMD ----------
// Wave = 16 q-rows, one KV chunk. 256-thread blocks (4 waves). Register-direct K/V,
// no-max base-2 softmax, cvt_pk pack, wave-private 2KB P-LDS, ones-MFMA lsum.
__device__ __forceinline__ int map16(int win, int t){
  return (((win >> 2)*16 + (t >> 4)) << 6) + ((win & 3) << 4) + (t & 15);
}

__global__ __launch_bounds__(256)
void k_flash(const unsigned short* __restrict__ qb, const unsigned short* __restrict__ kb,
             const unsigned short* __restrict__ vtb, const float* __restrict__ b256,
             unsigned short* __restrict__ fsp,
             unsigned short* __restrict__ pO, float* __restrict__ pl)
{
  __shared__ unsigned short Pp[4][1024];           // per-wave P: 16x64 bf16 (2KB)
  const int t = threadIdx.x, l = t & 63, w = t >> 6;
  const int lr = l & 15, lg = l >> 4;
  const int v = (blockIdx.x & 7)*640 + (blockIdx.x >> 3);   // XCD-pinned, 5120 blocks
  const int b = v / 640, u = v % 640;
  const int wu = u*4 + w;                          // wave unit within batch (0..2559)
  int h, win, s0, s1, chunk = 0, qsub;
  const float* btab = nullptr;
  if (wu < 2048){ h = 0; win = wu >> 7; chunk = (wu >> 4) & 7; qsub = wu & 15;
                  s0 = chunk*8; s1 = s0 + 8; }
  else { int uu = wu - 2048; h = 6 + (uu >> 8); win = (uu >> 4) & 15; qsub = uu & 15;
         s0 = 0; s1 = 4; btab = b256 + ((size_t)(h - 6) << 16); }
  const int qoff = qsub*16;
  const size_t hb = ((size_t)(b*8 + h)) << 18;
  const float SC = 0.125f * LOG2E;

  char* pw = (char*)Pp[w];
  bf16x8 ones8;
  #pragma unroll
  for (int e = 0; e < 8; e++) ones8[e] = (short)0x3F80;

  bf16x8 qf[2];
  {
    int qt = qoff + lr;
    int n = (h == 0) ? (win*256 + qt) : map16(win, qt);
    const unsigned short* qp = qb + hb + ((size_t)n << 6) + lg*8;
    qf[0] = *(const bf16x8*)qp;
    qf[1] = *(const bf16x8*)(qp + 32);
  }
  f32x4 ao[4] = {};
  f32x4 lsum4 = {};

  for (int s = s0; s < s1; s++){
    // QK^T + pack, nf-paired to keep sv liveness at 8 VGPR
    #pragma unroll
    for (int nfp = 0; nfp < 2; nfp++){
      bf16x8 kf[2][2];
      #pragma unroll
      for (int kt = 0; kt < 2; kt++)
        #pragma unroll
        for (int nfi = 0; nfi < 2; nfi++){
          int tk = s*64 + (nfp*2 + nfi)*16 + lr;
          int nk = (h == 0) ? tk : map16(win, tk);
          kf[kt][nfi] = *(const bf16x8*)(kb + hb + ((size_t)nk << 6) + kt*32 + lg*8);
        }
      f32x4 sv[2] = {};
      #pragma unroll
      for (int kt = 0; kt < 2; kt++)
        #pragma unroll
        for (int nfi = 0; nfi < 2; nfi++)
          sv[nfi] = MFMA(qf[kt], kf[kt][nfi], sv[nfi]);
      #pragma unroll
      for (int r = 0; r < 4; r++){
        int nfA = nfp*2, nfB = nfp*2 + 1;
        float xa, xb_;
        if (btab){
          int qw = qoff + lg*4 + r;
          xa = __builtin_fmaf(sv[0][r], SC, btab[(qw << 8) + s*64 + nfA*16 + lr]);
          xb_= __builtin_fmaf(sv[1][r], SC, btab[(qw << 8) + s*64 + nfB*16 + lr]);
        } else {
          xa = sv[0][r] * SC;
          xb_= sv[1][r] * SC;
        }
        unsigned pk = cvt_pk_bf16(fast_exp2(xa), fast_exp2(xb_));
        int row = lg*4 + r;
        int swz = (row & 7) << 4;
        *(unsigned short*)(pw + row*128 + (((nfA*16 + lr)*2) ^ swz)) = (unsigned short)pk;
        *(unsigned short*)(pw + row*128 + (((nfB*16 + lr)*2) ^ swz)) = (unsigned short)(pk >> 16);
      }
    }
    // PV + lsum
    #pragma unroll
    for (int kg = 0; kg < 2; kg++){
      bf16x8 pa, vf[4];
      {
        int cb = (kg*64 + lg*16) ^ ((lr & 7) << 4);
        pa = *(const bf16x8*)(pw + lr*128 + cb);
      }
      int tv = s*64 + kg*32 + lg*8;
      int nv = (h == 0) ? tv : map16(win, tv);
      #pragma unroll
      for (int df = 0; df < 4; df++)
        vf[df] = *(const bf16x8*)(vtb + hb + ((size_t)(df*16 + lr) << 12) + nv);
      #pragma unroll
      for (int df = 0; df < 4; df++)
        ao[df] = MFMA(pa, vf[df], ao[df]);
      lsum4 = MFMA(pa, ones8, lsum4);
    }
  }

  if (h == 0){
    #pragma unroll
    for (int r = 0; r < 4; r++){
      int qt = qoff + lg*4 + r;
      size_t rowb = (((size_t)(b*8 + chunk)) << 12) + win*256 + qt;
      if (lr == 0) pl[rowb] = lsum4[r];
      #pragma unroll
      for (int df = 0; df < 4; df++)
        pO[(rowb << 6) + df*16 + lr] = f2bf(ao[df][r]);
    }
  } else {
    #pragma unroll
    for (int df = 0; df < 4; df++)
      #pragma unroll
      for (int r = 0; r < 4; r++){
        float o = ao[df][r] / lsum4[r];
        int np = win*256 + qoff + lg*4 + r;
        fsp[(((size_t)b*4096 + np) << 9) + h*64 + df*16 + lr] = f2bf(o);
      }
  }
}

// ---------- combine head-0 KV chunks (plain sums) ----------
__global__ __launch_bounds__(256)
void k_comb(const unsigned short* __restrict__ pO, const float* __restrict__ pl,
            unsigned short* __restrict__ fsp){
  int tid = blockIdx.x*256 + threadIdx.x;      // 2M = 32768 rows * 64 d
  int d = tid & 63;
  int row = tid >> 6;
  int b = row >> 12;
  int n = row & 4095;
  float o = 0.f, L = 0.f;
  #pragma unroll
  for (int c = 0; c < 8; c++){
    size_t rr = (((size_t)(b*8 + c)) << 12) + n;
    L += pl[rr];
    o += bf2f(pO[(rr << 6) + d]);
  }
  o /= L;
  fsp[(((size_t)b*4096 + n) << 9) + d] = f2bf(o);
}

// ---------- 64-token window attention (heads 1..5), R12-validated ----------
__device__ __forceinline__ int mapw(int h, int u, int t){
  if (h <= 2) return (((u >> 2)*4 + (t >> 4)) << 6) + ((u & 3) << 4) + (t & 15);
  return (((u >> 3)*8 + (t >> 3)) << 6) + ((u & 7) << 3) + (t & 7);
}

__global__ __launch_bounds__(256, 2)
void k_win64(const unsigned short* __restrict__ qb, const unsigned short* __restrict__ kb,
             const unsigned short* __restrict__ vtb, const float* __restrict__ b64,
             unsigned short* __restrict__ fsp)
{
  __shared__ unsigned short KP[4][64*64];
  __shared__ unsigned short Vw[4][64*64];
  const int t = threadIdx.x, l = t & 63, w = t >> 6;
  const int lr = l & 15, lg = l >> 4;
  const int gid = blockIdx.x*4 + w;
  const int b = gid / 320;
  const int rem = gid % 320;
  const int h = 1 + (rem >> 6);
  const int u = rem & 63;
  const size_t hb = ((size_t)(b*8 + h)) << 18;
  const float SC = 0.125f * LOG2E;

  #pragma unroll
  for (int i = 0; i < 8; i++){
    int row = i*8 + (l >> 3);
    int sc  = (((l & 7) ^ (row & 7)) << 3);
    gload16(kb  + hb + ((size_t)mapw(h,u,row) << 6) + sc, &KP[w][i*512]);
    gload16(vtb + hb + ((size_t)row << 12) + mapw(h,u,sc), &Vw[w][i*512]);
  }
  bf16x8 qf[4][2];
  #pragma unroll
  for (int mf = 0; mf < 4; mf++){
    int n = mapw(h, u, mf*16 + lr);
    const unsigned short* qp = qb + hb + ((size_t)n << 6) + lg*8;
    qf[mf][0] = *(const bf16x8*)qp;
    qf[mf][1] = *(const bf16x8*)(qp + 32);
  }
  __syncthreads();

  const char* kpc = (const char*)KP[w];
  const char* vwc = (const char*)Vw[w];
  f32x4 sv[4][4] = {};
  #pragma unroll
  for (int kt = 0; kt < 2; kt++){
    bf16x8 kf[4];
    #pragma unroll
    for (int nf = 0; nf < 4; nf++){
      int row = nf*16 + lr;
      int cb  = (kt*64 + lg*16) ^ ((row & 7) << 4);
      kf[nf] = *(const bf16x8*)(kpc + row*128 + cb);
    }
    #pragma unroll
    for (int mf = 0; mf < 4; mf++)
      #pragma unroll
      for (int nf = 0; nf < 4; nf++)
        sv[mf][nf] = MFMA(qf[mf][kt], kf[nf], sv[mf][nf]);
  }
  const float* bt = b64 + ((size_t)(h-1) << 12);
  float li[4][4];
  #pragma unroll
  for (int mf = 0; mf < 4; mf++)
    #pragma unroll
    for (int r = 0; r < 4; r++){
      int qt = mf*16 + lg*4 + r;
      #pragma unroll
      for (int nf = 0; nf < 4; nf++)
        sv[mf][nf][r] = __builtin_fmaf(sv[mf][nf][r], SC, bt[(qt << 6) + nf*16 + lr]);
      float mx = fmaxf(fmaxf(sv[mf][0][r], sv[mf][1][r]), fmaxf(sv[mf][2][r], sv[mf][3][r]));
      mx = fmaxf(mx, __shfl_xor(mx, 1));
      mx = fmaxf(mx, __shfl_xor(mx, 2));
      mx = fmaxf(mx, __shfl_xor(mx, 4));
      mx = fmaxf(mx, __shfl_xor(mx, 8));
      float rs = 0.f;
      #pragma unroll
      for (int nf = 0; nf < 4; nf++){
        float p = fast_exp2(sv[mf][nf][r] - mx);
        sv[mf][nf][r] = p; rs += p;
      }
      rs += __shfl_xor(rs, 1); rs += __shfl_xor(rs, 2);
      rs += __shfl_xor(rs, 4); rs += __shfl_xor(rs, 8);
      li[mf][r] = rs;
    }
  char* pw = (char*)KP[w];
  #pragma unroll
  for (int mf = 0; mf < 4; mf++)
    #pragma unroll
    for (int nf = 0; nf < 4; nf++)
      #pragma unroll
      for (int r = 0; r < 4; r++){
        int row = mf*16 + lg*4 + r;
        int cb  = ((nf*16 + lr)*2) ^ ((row & 7) << 4);
        *(unsigned short*)(pw + row*128 + cb) = f2bf(sv[mf][nf][r]);
      }
  f32x4 ao[4][4] = {};
  #pragma unroll
  for (int kg = 0; kg < 2; kg++){
    bf16x8 pa[4], vf[4];
    #pragma unroll
    for (int mf = 0; mf < 4; mf++){
      int row = mf*16 + lr;
      int cb  = (kg*64 + lg*16) ^ ((row & 7) << 4);
      pa[mf] = *(const bf16x8*)(pw + row*128 + cb);
    }
    #pragma unroll
    for (int df = 0; df < 4; df++){
      int row = df*16 + lr;
      int cb  = (kg*64 + lg*16) ^ ((row & 7) << 4);
      vf[df] = *(const bf16x8*)(vwc + row*128 + cb);
    }
    #pragma unroll
    for (int mf = 0; mf < 4; mf++)
      #pragma unroll
      for (int df = 0; df < 4; df++)
        ao[mf][df] = MFMA(pa[mf], vf[df], ao[mf][df]);
  }
  #pragma unroll
  for (int mf = 0; mf < 4; mf++)
    #pragma unroll
    for (int df = 0; df < 4; df++)
      #pragma unroll
      for (int r = 0; r < 4; r++){
        float o = ao[mf][df][r] / li[mf][r];
        int qt = mf*16 + lg*4 + r;
        int np;
        if (h <= 2){
          int r4 = qt >> 4, w_ = (qt >> 2) & 3, c = qt & 3;
          np = (u >> 2)*256 + (u & 3)*64 + w_*16 + r4*4 + c;
        } else {
          np = u*64 + qt;
        }
        fsp[(((size_t)b*4096 + np) << 9) + h*64 + df*16 + lr] = f2bf(o);
      }
}

// ---------- launch ----------
extern "C" void kernel_launch(void* const* d_in, const int* in_sizes, int n_in,
                              void* d_out, int out_size, void* d_ws, size_t ws_size,
                              hipStream_t stream) {
  const float* x     = (const float*)d_in[0];
  const float* Wq    = (const float*)d_in[1];
  const float* Wkv   = (const float*)d_in[2];
  const float* Wp    = (const float*)d_in[3];
  const float* bproj = (const float*)d_in[4];
  const float* t1 = (const float*)d_in[7];
  const float* t2 = (const float*)d_in[8];
  const float* t3 = (const float*)d_in[9];
  const float* t4 = (const float*)d_in[10];
  const float* t5 = (const float*)d_in[11];
  const float* t6 = (const float*)d_in[12];
  const float* t7 = (const float*)d_in[13];

  char* W = (char*)d_ws;
  size_t off = 0;
  auto alloc = [&](size_t bytes)->char*{
    char* p = W + off; off += (bytes + 255) & ~(size_t)255; return p;
  };
  unsigned short* xb   = (unsigned short*)alloc((size_t)32768*512*2);   // dead after gemm0
  unsigned short* wqkv = (unsigned short*)alloc((size_t)1536*512*2);    // dead after gemm0
  unsigned short* wsp  = (unsigned short*)alloc((size_t)512*512*2);
  unsigned short* qbuf = (unsigned short*)alloc((size_t)8*8*4096*64*2);
  unsigned short* kbuf = (unsigned short*)alloc((size_t)8*8*4096*64*2);
  unsigned short* vtb  = (unsigned short*)alloc((size_t)8*8*4096*64*2);
  unsigned short* fsp  = (unsigned short*)alloc((size_t)32768*512*2);
  float* b64  = (float*)alloc((size_t)5*64*64*4);
  float* b256 = (float*)alloc((size_t)2*256*256*4);
  if (off > ws_size) return;

  // head-0 partials alias dead regions (flash runs after gemm0):
  unsigned short* pO = xb;                 // (8b*8c)*4096 rows * 64 d * 2B = 32 MiB
  float* pl = (float*)wqkv;                // 64*4096*4B = 1 MiB

  k_conv_x<<<8192, 256, 0, stream>>>(x, xb, 32768*512);
  k_prep<<<640, 256, 0, stream>>>(Wq, Wkv, Wp, t1,t2,t3,t4,t5,t6,t7,
                                  wqkv, wsp, b64, b256);

  k_gemm<0><<<3072, 256, 0, stream>>>(xb, wqkv, 32768,
                                      qbuf, kbuf, vtb, nullptr, nullptr);
  k_flash<<<5120, 256, 0, stream>>>(qbuf, kbuf, vtb, b256, fsp, pO, pl);
  k_comb<<<8192, 256, 0, stream>>>(pO, pl, fsp);
  k_win64<<<640, 256, 0, stream>>>(qbuf, kbuf, vtb, b64, fsp);
  k_gemm<1><<<1024, 256, 0, stream>>>(fsp, wsp, 32768,
                                      nullptr, nullptr, nullptr, (float*)d_out, bproj);
}

// Round 15
// 267.908 us; speedup vs baseline: 1.6658x; 1.6658x over previous
//
#include <hip/hip_runtime.h>
#include <stdint.h>

typedef __attribute__((ext_vector_type(8))) short bf16x8;
typedef __attribute__((ext_vector_type(4))) float f32x4;

#define LOG2E 1.4426950408889634f

__device__ __forceinline__ unsigned short f2bf(float f){
  union { float f; unsigned u; } v; v.f = f;
  return (unsigned short)((v.u + 0x7fffu + ((v.u >> 16) & 1u)) >> 16);
}
__device__ __forceinline__ float bf2f(unsigned short h){
  union { unsigned u; float f; } v; v.u = ((unsigned)h) << 16; return v.f;
}
__device__ __forceinline__ float fast_exp2(float x){
  float r; asm("v_exp_f32 %0, %1" : "=v"(r) : "v"(x)); return r;
}
__device__ __forceinline__ unsigned cvt_pk_bf16(float lo, float hi){
  unsigned r; asm("v_cvt_pk_bf16_f32 %0, %1, %2" : "=v"(r) : "v"(lo), "v"(hi)); return r;
}
__device__ __forceinline__ void gload16(const void* g, void* lds){
  __builtin_amdgcn_global_load_lds((const __attribute__((address_space(1))) unsigned int*)g,
                                   (__attribute__((address_space(3))) unsigned int*)lds,
                                   16, 0, 0);
}
#define MFMA(a,b,c) __builtin_amdgcn_mfma_f32_16x16x32_bf16((a),(b),(c),0,0,0)

// B=8, H=W=64, N=4096, C=512, nh=8, hd=64

__global__ void k_conv_x(const float* __restrict__ x, unsigned short* __restrict__ xb, int n){
  int i = (blockIdx.x*256 + threadIdx.x)*8;
  if (i >= n) return;
  float4 a = *(const float4*)(x+i);
  float4 b = *(const float4*)(x+i+4);
  *(ushort4*)(xb+i)   = make_ushort4(f2bf(a.x), f2bf(a.y), f2bf(a.z), f2bf(a.w));
  *(ushort4*)(xb+i+4) = make_ushort4(f2bf(b.x), f2bf(b.y), f2bf(b.z), f2bf(b.w));
}

// Merged prep: weights + bias tables (tables pre-scaled by log2(e) for base-2 softmax).
__global__ void k_prep(const float* __restrict__ Wq, const float* __restrict__ Wkv,
                       const float* __restrict__ Wp,
                       const float* t1,const float* t2,const float* t3,const float* t4,
                       const float* t5,const float* t6,const float* t7,
                       unsigned short* __restrict__ wqkv, unsigned short* __restrict__ wsp,
                       float* __restrict__ b64, float* __restrict__ b256){
  int i = blockIdx.x*256 + threadIdx.x;
  int stride = gridDim.x*256;
  for (int e = i; e < 1536*512; e += stride){
    int r = e >> 9;
    wqkv[e] = f2bf(r < 512 ? Wq[e] : Wkv[e - 512*512]);
  }
  for (int e = i; e < 512*512; e += stride)
    wsp[e] = f2bf(Wp[e]);
  for (int e = i; e < 5*4096; e += stride){
    int hh = e >> 12;
    int q = (e >> 6) & 63, kk = e & 63;
    float v;
    if (hh < 2){                       // p=4: unit token t = r*16 + i*4 + c, strip mask
      const float* tb = hh ? t2 : t1;
      int r1=q>>4, i1=(q>>2)&3, c1=q&3;
      int r2=kk>>4, i2=(kk>>2)&3, c2=kk&3;
      v = (i1==i2) ? tb[(r1-r2+3)*7 + (c1-c2+3)] : -1e30f;
    } else {                           // p=8: t = r*8 + c
      const float* tb = (hh==2)?t3:((hh==3)?t4:t5);
      int r1=q>>3, c1=q&7, r2=kk>>3, c2=kk&7;
      v = tb[(r1-r2+7)*15 + (c1-c2+7)];
    }
    b64[e] = v * LOG2E;
  }
  for (int e = i; e < 2*65536; e += stride){
    int hh = e >> 16; int q = (e >> 8) & 255, kk = e & 255;
    const float* tb = hh ? t7 : t6;
    int r1=q>>4, c1=q&15, r2=kk>>4, c2=kk&15;
    b256[e] = tb[(r1-r2+15)*31 + (c1-c2+15)] * LOG2E;
  }
}

// ---------- GEMM (validated), K=512 for both uses ----------
template<int EPI>
__global__ __launch_bounds__(256, 2)
void k_gemm(const unsigned short* __restrict__ A, const unsigned short* __restrict__ Bw,
            int M,
            unsigned short* __restrict__ oq, unsigned short* __restrict__ ok,
            unsigned short* __restrict__ ovt,
            float* __restrict__ of, const float* __restrict__ bias)
{
  __shared__ unsigned short As[128*64];
  __shared__ unsigned short Bs[128*64];
  const int t = threadIdx.x, l = t & 63, w = t >> 6;
  const int mt = M >> 7;
  const int bm = blockIdx.x % mt, bn = blockIdx.x / mt;
  const int m0 = bm << 7, n0 = bn << 7;
  const int wr = w >> 1, wc = w & 1;
  const int lr = l & 15, lg = l >> 4;
  f32x4 acc[4][4] = {};

  for (int k0 = 0; k0 < 512; k0 += 64){
    #pragma unroll
    for (int i = 0; i < 4; i++){
      int rowb = i*32 + w*8;
      int row  = rowb + (l >> 3);
      int sc   = (((l & 7) ^ (row & 7)) << 3);
      gload16(A  + (size_t)(m0 + row)*512 + k0 + sc, &As[rowb*64]);
      gload16(Bw + (size_t)(n0 + row)*512 + k0 + sc, &Bs[rowb*64]);
    }
    __syncthreads();
    #pragma unroll
    for (int kt = 0; kt < 2; kt++){
      bf16x8 af[4], bfr[4];
      #pragma unroll
      for (int mi = 0; mi < 4; mi++){
        int row = wr*64 + mi*16 + lr;
        int cb  = (kt*64 + lg*16) ^ ((row & 7) << 4);
        af[mi] = *(const bf16x8*)((const char*)As + row*128 + cb);
      }
      #pragma unroll
      for (int ni = 0; ni < 4; ni++){
        int row = wc*64 + ni*16 + lr;
        int cb  = (kt*64 + lg*16) ^ ((row & 7) << 4);
        bfr[ni] = *(const bf16x8*)((const char*)Bs + row*128 + cb);
      }
      #pragma unroll
      for (int mi = 0; mi < 4; mi++)
        #pragma unroll
        for (int ni = 0; ni < 4; ni++)
          acc[mi][ni] = MFMA(af[mi], bfr[ni], acc[mi][ni]);
    }
    __syncthreads();
  }

  #pragma unroll
  for (int mi = 0; mi < 4; mi++){
    #pragma unroll
    for (int ni = 0; ni < 4; ni++){
      int m = m0 + wr*64 + mi*16 + lg*4;
      int o = n0 + wc*64 + ni*16 + lr;
      if (EPI == 0){
        int which = o >> 9, oo = o & 511, h = oo >> 6, d = oo & 63;
        int b_ = m >> 12, n_ = m & 4095;
        if (which == 2){
          *(ushort4*)(ovt + ((((size_t)b_*8 + h)*64 + d) << 12) + n_) =
            make_ushort4(f2bf(acc[mi][ni][0]), f2bf(acc[mi][ni][1]),
                         f2bf(acc[mi][ni][2]), f2bf(acc[mi][ni][3]));
        } else {
          unsigned short* dst = (which == 0) ? oq : ok;
          size_t base = (((size_t)(b_*8 + h)) << 18) + ((size_t)n_ << 6) + d;
          #pragma unroll
          for (int r = 0; r < 4; r++)
            dst[base + (size_t)r*64] = f2bf(acc[mi][ni][r]);
        }
      } else {
        float bv = bias[o];
        #pragma unroll
        for (int r = 0; r < 4; r++)
          of[(size_t)(m + r)*512 + o] = acc[mi][ni][r] + bv;
      }
    }
  }
}

// ---------- flash (h0 + h6/7): R12 structure, K/V via block-staged dbuf LDS ----------
// Block = 8 waves x 32 q-rows sharing one KV chunk. Per step: issue stage(s+1) ->
// compute(s) from LDS -> vmcnt(0) -> barrier. Staging moves scattered fragment reads
// off the TA pipe (16 lines/instr x 16/step/wave) onto coalesced gload16 + LDS reads.
__device__ __forceinline__ int map16(int win, int t){
  return (((win >> 2)*16 + (t >> 4)) << 6) + ((win & 3) << 4) + (t & 15);
}

__global__ __launch_bounds__(512)
void k_flash(const unsigned short* __restrict__ qb, const unsigned short* __restrict__ kb,
             const unsigned short* __restrict__ vtb, const float* __restrict__ b256,
             unsigned short* __restrict__ fsp,
             unsigned short* __restrict__ pO, float* __restrict__ pl)
{
  __shared__ unsigned short KV[2][8192];           // [K 64x64 | V^T 64x64] per buffer
  __shared__ unsigned short Pp[8][2048];           // per-wave P: 32x64 bf16
  const int t = threadIdx.x, l = t & 63, w = t >> 6;
  const int lr = l & 15, lg = l >> 4;
  const int v = (blockIdx.x & 7)*160 + (blockIdx.x >> 3);   // XCD-pinned, 1280 blocks
  const int b = v / 160, u = v % 160;
  int h, win, s0, s1, chunk = 0;
  const float* btab = nullptr;
  if (u < 128){ h = 0; win = u >> 3; chunk = u & 7; s0 = chunk*8; s1 = s0 + 8; }
  else { int uu = u - 128; h = 6 + (uu >> 4); win = uu & 15; s0 = 0; s1 = 4;
         btab = b256 + ((size_t)(h - 6) << 16); }
  const size_t hb = ((size_t)(b*8 + h)) << 18;
  const float SC = 0.125f * LOG2E;

  // staging role: wave w covers rows w*8..w*8+7 (K tokens / V d-rows)
  const int srow = w*8 + (l >> 3);
  const int ssc  = (((l & 7) ^ (srow & 7)) << 3);   // inverse-swizzled source col

  char* pw = (char*)Pp[w];
  bf16x8 ones8;
  #pragma unroll
  for (int e = 0; e < 8; e++) ones8[e] = (short)0x3F80;

  bf16x8 qf[2][2];
  #pragma unroll
  for (int mf = 0; mf < 2; mf++){
    int qt = w*32 + mf*16 + lr;
    int n = (h == 0) ? (win*256 + qt) : map16(win, qt);
    const unsigned short* qp = qb + hb + ((size_t)n << 6) + lg*8;
    qf[mf][0] = *(const bf16x8*)qp;
    qf[mf][1] = *(const bf16x8*)(qp + 32);
  }
  f32x4 ao[2][4] = {};
  f32x4 lsum4[2] = {};

  auto stage = [&](int s, int buf){
    int tk = s*64 + srow;
    int nk = (h == 0) ? tk : map16(win, tk);
    gload16(kb + hb + ((size_t)nk << 6) + ssc, &KV[buf][w*512]);
    int tv = s*64 + ssc;
    int nv = (h == 0) ? tv : map16(win, tv);
    gload16(vtb + hb + ((size_t)srow << 12) + nv, &KV[buf][4096 + w*512]);
  };

  stage(s0, 0);
  asm volatile("s_waitcnt vmcnt(0)" ::: "memory");
  __builtin_amdgcn_s_barrier();

  for (int s = s0; s < s1; s++){
    const int cur = (s - s0) & 1;
    if (s + 1 < s1) stage(s + 1, cur ^ 1);
    const char* kpc = (const char*)&KV[cur][0];
    const char* vpc = (const char*)&KV[cur][4096];

    // QK^T from LDS K (swizzled ds_read_b128)
    f32x4 sv[2][4] = {};
    #pragma unroll
    for (int kt = 0; kt < 2; kt++){
      bf16x8 kf[4];
      #pragma unroll
      for (int nf = 0; nf < 4; nf++){
        int row = nf*16 + lr;
        int cb  = (kt*64 + lg*16) ^ ((row & 7) << 4);
        kf[nf] = *(const bf16x8*)(kpc + row*128 + cb);
      }
      #pragma unroll
      for (int mf = 0; mf < 2; mf++)
        #pragma unroll
        for (int nf = 0; nf < 4; nf++)
          sv[mf][nf] = MFMA(qf[mf][kt], kf[nf], sv[mf][nf]);
    }
    // base-2 softmax (no shift) + cvt_pk pack -> wave-private LDS (swizzled)
    #pragma unroll
    for (int mf = 0; mf < 2; mf++)
      #pragma unroll
      for (int nfp = 0; nfp < 2; nfp++)
        #pragma unroll
        for (int r = 0; r < 4; r++){
          int nfA = nfp*2, nfB = nfp*2 + 1;
          float xa, xb_;
          if (btab){
            int qw = w*32 + mf*16 + lg*4 + r;
            xa = __builtin_fmaf(sv[mf][nfA][r], SC, btab[(qw << 8) + s*64 + nfA*16 + lr]);
            xb_= __builtin_fmaf(sv[mf][nfB][r], SC, btab[(qw << 8) + s*64 + nfB*16 + lr]);
          } else {
            xa = sv[mf][nfA][r] * SC;
            xb_= sv[mf][nfB][r] * SC;
          }
          unsigned pk = cvt_pk_bf16(fast_exp2(xa), fast_exp2(xb_));
          int row = mf*16 + lg*4 + r;
          int swz = (row & 7) << 4;
          *(unsigned short*)(pw + row*128 + (((nfA*16 + lr)*2) ^ swz)) = (unsigned short)pk;
          *(unsigned short*)(pw + row*128 + (((nfB*16 + lr)*2) ^ swz)) = (unsigned short)(pk >> 16);
        }
    // PV from LDS V (swizzled) + lsum via ones-MFMA
    #pragma unroll
    for (int kg = 0; kg < 2; kg++){
      bf16x8 pa[2], vf[4];
      #pragma unroll
      for (int mf = 0; mf < 2; mf++){
        int row = mf*16 + lr;
        int cb  = (kg*64 + lg*16) ^ ((row & 7) << 4);
        pa[mf] = *(const bf16x8*)(pw + row*128 + cb);
      }
      #pragma unroll
      for (int df = 0; df < 4; df++){
        int row = df*16 + lr;
        int cb  = (kg*64 + lg*16) ^ ((row & 7) << 4);
        vf[df] = *(const bf16x8*)(vpc + row*128 + cb);
      }
      #pragma unroll
      for (int mf = 0; mf < 2; mf++){
        #pragma unroll
        for (int df = 0; df < 4; df++)
          ao[mf][df] = MFMA(pa[mf], vf[df], ao[mf][df]);
        lsum4[mf] = MFMA(pa[mf], ones8, lsum4[mf]);
      }
    }
    asm volatile("s_waitcnt vmcnt(0)" ::: "memory");   // next-tile staging landed
    __builtin_amdgcn_s_barrier();                      // all waves done with buf[cur]
  }

  if (h == 0){
    #pragma unroll
    for (int mf = 0; mf < 2; mf++)
      #pragma unroll
      for (int r = 0; r < 4; r++){
        int qt = w*32 + mf*16 + lg*4 + r;
        size_t rowb = (((size_t)(b*8 + chunk)) << 12) + win*256 + qt;
        if (lr == 0) pl[rowb] = lsum4[mf][r];
        #pragma unroll
        for (int df = 0; df < 4; df++)
          pO[(rowb << 6) + df*16 + lr] = f2bf(ao[mf][df][r]);
      }
  } else {
    #pragma unroll
    for (int mf = 0; mf < 2; mf++)
      #pragma unroll
      for (int df = 0; df < 4; df++)
        #pragma unroll
        for (int r = 0; r < 4; r++){
          float o = ao[mf][df][r] / lsum4[mf][r];
          int qt = w*32 + mf*16 + lg*4 + r;
          int np = win*256 + qt;
          fsp[(((size_t)b*4096 + np) << 9) + h*64 + df*16 + lr] = f2bf(o);
        }
  }
}

// ---------- combine head-0 KV chunks (plain sums) ----------
__global__ __launch_bounds__(256)
void k_comb(const unsigned short* __restrict__ pO, const float* __restrict__ pl,
            unsigned short* __restrict__ fsp){
  int tid = blockIdx.x*256 + threadIdx.x;      // 2M = 32768 rows * 64 d
  int d = tid & 63;
  int row = tid >> 6;
  int b = row >> 12;
  int n = row & 4095;
  float o = 0.f, L = 0.f;
  #pragma unroll
  for (int c = 0; c < 8; c++){
    size_t rr = (((size_t)(b*8 + c)) << 12) + n;
    L += pl[rr];
    o += bf2f(pO[(rr << 6) + d]);
  }
  o /= L;
  fsp[(((size_t)b*4096 + n) << 9) + d] = f2bf(o);
}

// ---------- 64-token window attention (heads 1..5), R12-validated ----------
__device__ __forceinline__ int mapw(int h, int u, int t){
  if (h <= 2) return (((u >> 2)*4 + (t >> 4)) << 6) + ((u & 3) << 4) + (t & 15);
  return (((u >> 3)*8 + (t >> 3)) << 6) + ((u & 7) << 3) + (t & 7);
}

__global__ __launch_bounds__(256, 2)
void k_win64(const unsigned short* __restrict__ qb, const unsigned short* __restrict__ kb,
             const unsigned short* __restrict__ vtb, const float* __restrict__ b64,
             unsigned short* __restrict__ fsp)
{
  __shared__ unsigned short KP[4][64*64];
  __shared__ unsigned short Vw[4][64*64];
  const int t = threadIdx.x, l = t & 63, w = t >> 6;
  const int lr = l & 15, lg = l >> 4;
  const int gid = blockIdx.x*4 + w;
  const int b = gid / 320;
  const int rem = gid % 320;
  const int h = 1 + (rem >> 6);
  const int u = rem & 63;
  const size_t hb = ((size_t)(b*8 + h)) << 18;
  const float SC = 0.125f * LOG2E;

  #pragma unroll
  for (int i = 0; i < 8; i++){
    int row = i*8 + (l >> 3);
    int sc  = (((l & 7) ^ (row & 7)) << 3);
    gload16(kb  + hb + ((size_t)mapw(h,u,row) << 6) + sc, &KP[w][i*512]);
    gload16(vtb + hb + ((size_t)row << 12) + mapw(h,u,sc), &Vw[w][i*512]);
  }
  bf16x8 qf[4][2];
  #pragma unroll
  for (int mf = 0; mf < 4; mf++){
    int n = mapw(h, u, mf*16 + lr);
    const unsigned short* qp = qb + hb + ((size_t)n << 6) + lg*8;
    qf[mf][0] = *(const bf16x8*)qp;
    qf[mf][1] = *(const bf16x8*)(qp + 32);
  }
  __syncthreads();

  const char* kpc = (const char*)KP[w];
  const char* vwc = (const char*)Vw[w];
  f32x4 sv[4][4] = {};
  #pragma unroll
  for (int kt = 0; kt < 2; kt++){
    bf16x8 kf[4];
    #pragma unroll
    for (int nf = 0; nf < 4; nf++){
      int row = nf*16 + lr;
      int cb  = (kt*64 + lg*16) ^ ((row & 7) << 4);
      kf[nf] = *(const bf16x8*)(kpc + row*128 + cb);
    }
    #pragma unroll
    for (int mf = 0; mf < 4; mf++)
      #pragma unroll
      for (int nf = 0; nf < 4; nf++)
        sv[mf][nf] = MFMA(qf[mf][kt], kf[nf], sv[mf][nf]);
  }
  const float* bt = b64 + ((size_t)(h-1) << 12);
  float li[4][4];
  #pragma unroll
  for (int mf = 0; mf < 4; mf++)
    #pragma unroll
    for (int r = 0; r < 4; r++){
      int qt = mf*16 + lg*4 + r;
      #pragma unroll
      for (int nf = 0; nf < 4; nf++)
        sv[mf][nf][r] = __builtin_fmaf(sv[mf][nf][r], SC, bt[(qt << 6) + nf*16 + lr]);
      float mx = fmaxf(fmaxf(sv[mf][0][r], sv[mf][1][r]), fmaxf(sv[mf][2][r], sv[mf][3][r]));
      mx = fmaxf(mx, __shfl_xor(mx, 1));
      mx = fmaxf(mx, __shfl_xor(mx, 2));
      mx = fmaxf(mx, __shfl_xor(mx, 4));
      mx = fmaxf(mx, __shfl_xor(mx, 8));
      float rs = 0.f;
      #pragma unroll
      for (int nf = 0; nf < 4; nf++){
        float p = fast_exp2(sv[mf][nf][r] - mx);
        sv[mf][nf][r] = p; rs += p;
      }
      rs += __shfl_xor(rs, 1); rs += __shfl_xor(rs, 2);
      rs += __shfl_xor(rs, 4); rs += __shfl_xor(rs, 8);
      li[mf][r] = rs;
    }
  char* pw = (char*)KP[w];
  #pragma unroll
  for (int mf = 0; mf < 4; mf++)
    #pragma unroll
    for (int nf = 0; nf < 4; nf++)
      #pragma unroll
      for (int r = 0; r < 4; r++){
        int row = mf*16 + lg*4 + r;
        int cb  = ((nf*16 + lr)*2) ^ ((row & 7) << 4);
        *(unsigned short*)(pw + row*128 + cb) = f2bf(sv[mf][nf][r]);
      }
  f32x4 ao[4][4] = {};
  #pragma unroll
  for (int kg = 0; kg < 2; kg++){
    bf16x8 pa[4], vf[4];
    #pragma unroll
    for (int mf = 0; mf < 4; mf++){
      int row = mf*16 + lr;
      int cb  = (kg*64 + lg*16) ^ ((row & 7) << 4);
      pa[mf] = *(const bf16x8*)(pw + row*128 + cb);
    }
    #pragma unroll
    for (int df = 0; df < 4; df++){
      int row = df*16 + lr;
      int cb  = (kg*64 + lg*16) ^ ((row & 7) << 4);
      vf[df] = *(const bf16x8*)(vwc + row*128 + cb);
    }
    #pragma unroll
    for (int mf = 0; mf < 4; mf++)
      #pragma unroll
      for (int df = 0; df < 4; df++)
        ao[mf][df] = MFMA(pa[mf], vf[df], ao[mf][df]);
  }
  #pragma unroll
  for (int mf = 0; mf < 4; mf++)
    #pragma unroll
    for (int df = 0; df < 4; df++)
      #pragma unroll
      for (int r = 0; r < 4; r++){
        float o = ao[mf][df][r] / li[mf][r];
        int qt = mf*16 + lg*4 + r;
        int np;
        if (h <= 2){
          int r4 = qt >> 4, w_ = (qt >> 2) & 3, c = qt & 3;
          np = (u >> 2)*256 + (u & 3)*64 + w_*16 + r4*4 + c;
        } else {
          np = u*64 + qt;
        }
        fsp[(((size_t)b*4096 + np) << 9) + h*64 + df*16 + lr] = f2bf(o);
      }
}

// ---------- launch ----------
extern "C" void kernel_launch(void* const* d_in, const int* in_sizes, int n_in,
                              void* d_out, int out_size, void* d_ws, size_t ws_size,
                              hipStream_t stream) {
  const float* x     = (const float*)d_in[0];
  const float* Wq    = (const float*)d_in[1];
  const float* Wkv   = (const float*)d_in[2];
  const float* Wp    = (const float*)d_in[3];
  const float* bproj = (const float*)d_in[4];
  const float* t1 = (const float*)d_in[7];
  const float* t2 = (const float*)d_in[8];
  const float* t3 = (const float*)d_in[9];
  const float* t4 = (const float*)d_in[10];
  const float* t5 = (const float*)d_in[11];
  const float* t6 = (const float*)d_in[12];
  const float* t7 = (const float*)d_in[13];

  char* W = (char*)d_ws;
  size_t off = 0;
  auto alloc = [&](size_t bytes)->char*{
    char* p = W + off; off += (bytes + 255) & ~(size_t)255; return p;
  };
  unsigned short* xb   = (unsigned short*)alloc((size_t)32768*512*2);   // dead after gemm0
  unsigned short* wqkv = (unsigned short*)alloc((size_t)1536*512*2);    // dead after gemm0
  unsigned short* wsp  = (unsigned short*)alloc((size_t)512*512*2);
  unsigned short* qbuf = (unsigned short*)alloc((size_t)8*8*4096*64*2);
  unsigned short* kbuf = (unsigned short*)alloc((size_t)8*8*4096*64*2);
  unsigned short* vtb  = (unsigned short*)alloc((size_t)8*8*4096*64*2);
  unsigned short* fsp  = (unsigned short*)alloc((size_t)32768*512*2);
  float* b64  = (float*)alloc((size_t)5*64*64*4);
  float* b256 = (float*)alloc((size_t)2*256*256*4);
  if (off > ws_size) return;

  // head-0 partials alias dead regions (flash runs after gemm0):
  unsigned short* pO = xb;                 // (8b*8c)*4096 rows * 64 d * 2B = 32 MiB
  float* pl = (float*)wqkv;                // 64*4096*4B = 1 MiB

  k_conv_x<<<8192, 256, 0, stream>>>(x, xb, 32768*512);
  k_prep<<<640, 256, 0, stream>>>(Wq, Wkv, Wp, t1,t2,t3,t4,t5,t6,t7,
                                  wqkv, wsp, b64, b256);

  k_gemm<0><<<3072, 256, 0, stream>>>(xb, wqkv, 32768,
                                      qbuf, kbuf, vtb, nullptr, nullptr);
  k_flash<<<1280, 512, 0, stream>>>(qbuf, kbuf, vtb, b256, fsp, pO, pl);
  k_comb<<<8192, 256, 0, stream>>>(pO, pl, fsp);
  k_win64<<<640, 256, 0, stream>>>(qbuf, kbuf, vtb, b64, fsp);
  k_gemm<1><<<1024, 256, 0, stream>>>(fsp, wsp, 32768,
                                      nullptr, nullptr, nullptr, (float*)d_out, bproj);
}

// Round 16
// 252.397 us; speedup vs baseline: 1.7682x; 1.0615x over previous
//
#include <hip/hip_runtime.h>
#include <stdint.h>

typedef __attribute__((ext_vector_type(8))) short bf16x8;
typedef __attribute__((ext_vector_type(4))) float f32x4;

#define LOG2E 1.4426950408889634f

__device__ __forceinline__ unsigned short f2bf(float f){
  union { float f; unsigned u; } v; v.f = f;
  return (unsigned short)((v.u + 0x7fffu + ((v.u >> 16) & 1u)) >> 16);
}
__device__ __forceinline__ float bf2f(unsigned short h){
  union { unsigned u; float f; } v; v.u = ((unsigned)h) << 16; return v.f;
}
__device__ __forceinline__ float fast_exp2(float x){
  float r; asm("v_exp_f32 %0, %1" : "=v"(r) : "v"(x)); return r;
}
__device__ __forceinline__ unsigned cvt_pk_bf16(float lo, float hi){
  unsigned r; asm("v_cvt_pk_bf16_f32 %0, %1, %2" : "=v"(r) : "v"(lo), "v"(hi)); return r;
}
__device__ __forceinline__ void gload16(const void* g, void* lds){
  __builtin_amdgcn_global_load_lds((const __attribute__((address_space(1))) unsigned int*)g,
                                   (__attribute__((address_space(3))) unsigned int*)lds,
                                   16, 0, 0);
}
#define MFMA(a,b,c) __builtin_amdgcn_mfma_f32_16x16x32_bf16((a),(b),(c),0,0,0)

// B=8, H=W=64, N=4096, C=512, nh=8, hd=64

// Merged prep: x->bf16 + weights + bias tables (pre-scaled by log2(e)).
__global__ __launch_bounds__(256)
void k_prep(const float* __restrict__ x, unsigned short* __restrict__ xb,
            const float* __restrict__ Wq, const float* __restrict__ Wkv,
            const float* __restrict__ Wp,
            const float* t1,const float* t2,const float* t3,const float* t4,
            const float* t5,const float* t6,const float* t7,
            unsigned short* __restrict__ wqkv, unsigned short* __restrict__ wsp,
            float* __restrict__ b64, float* __restrict__ b256){
  int gid = blockIdx.x*256 + threadIdx.x;
  int stride = gridDim.x*256;
  int i8 = gid*8;
  if (i8 < 32768*512){
    float4 a = *(const float4*)(x+i8);
    float4 bb = *(const float4*)(x+i8+4);
    *(ushort4*)(xb+i8)   = make_ushort4(f2bf(a.x), f2bf(a.y), f2bf(a.z), f2bf(a.w));
    *(ushort4*)(xb+i8+4) = make_ushort4(f2bf(bb.x), f2bf(bb.y), f2bf(bb.z), f2bf(bb.w));
  }
  for (int e = gid; e < 1536*512; e += stride){
    int r = e >> 9;
    wqkv[e] = f2bf(r < 512 ? Wq[e] : Wkv[e - 512*512]);
  }
  for (int e = gid; e < 512*512; e += stride)
    wsp[e] = f2bf(Wp[e]);
  for (int e = gid; e < 5*4096; e += stride){
    int hh = e >> 12;
    int q = (e >> 6) & 63, kk = e & 63;
    float v;
    if (hh < 2){                       // p=4: unit token t = r*16 + i*4 + c, strip mask
      const float* tb = hh ? t2 : t1;
      int r1=q>>4, i1=(q>>2)&3, c1=q&3;
      int r2=kk>>4, i2=(kk>>2)&3, c2=kk&3;
      v = (i1==i2) ? tb[(r1-r2+3)*7 + (c1-c2+3)] : -1e30f;
    } else {                           // p=8: t = r*8 + c
      const float* tb = (hh==2)?t3:((hh==3)?t4:t5);
      int r1=q>>3, c1=q&7, r2=kk>>3, c2=kk&7;
      v = tb[(r1-r2+7)*15 + (c1-c2+7)];
    }
    b64[e] = v * LOG2E;
  }
  for (int e = gid; e < 2*65536; e += stride){
    int hh = e >> 16; int q = (e >> 8) & 255, kk = e & 255;
    const float* tb = hh ? t7 : t6;
    int r1=q>>4, c1=q&15, r2=kk>>4, c2=kk&15;
    b256[e] = tb[(r1-r2+15)*31 + (c1-c2+15)] * LOG2E;
  }
}

// ---------- GEMM (validated), K=512 for both uses ----------
template<int EPI>
__global__ __launch_bounds__(256, 2)
void k_gemm(const unsigned short* __restrict__ A, const unsigned short* __restrict__ Bw,
            int M,
            unsigned short* __restrict__ oq, unsigned short* __restrict__ ok,
            unsigned short* __restrict__ ovt,
            float* __restrict__ of, const float* __restrict__ bias)
{
  __shared__ unsigned short As[128*64];
  __shared__ unsigned short Bs[128*64];
  const int t = threadIdx.x, l = t & 63, w = t >> 6;
  const int mt = M >> 7;
  const int bm = blockIdx.x % mt, bn = blockIdx.x / mt;
  const int m0 = bm << 7, n0 = bn << 7;
  const int wr = w >> 1, wc = w & 1;
  const int lr = l & 15, lg = l >> 4;
  f32x4 acc[4][4] = {};

  for (int k0 = 0; k0 < 512; k0 += 64){
    #pragma unroll
    for (int i = 0; i < 4; i++){
      int rowb = i*32 + w*8;
      int row  = rowb + (l >> 3);
      int sc   = (((l & 7) ^ (row & 7)) << 3);
      gload16(A  + (size_t)(m0 + row)*512 + k0 + sc, &As[rowb*64]);
      gload16(Bw + (size_t)(n0 + row)*512 + k0 + sc, &Bs[rowb*64]);
    }
    __syncthreads();
    #pragma unroll
    for (int kt = 0; kt < 2; kt++){
      bf16x8 af[4], bfr[4];
      #pragma unroll
      for (int mi = 0; mi < 4; mi++){
        int row = wr*64 + mi*16 + lr;
        int cb  = (kt*64 + lg*16) ^ ((row & 7) << 4);
        af[mi] = *(const bf16x8*)((const char*)As + row*128 + cb);
      }
      #pragma unroll
      for (int ni = 0; ni < 4; ni++){
        int row = wc*64 + ni*16 + lr;
        int cb  = (kt*64 + lg*16) ^ ((row & 7) << 4);
        bfr[ni] = *(const bf16x8*)((const char*)Bs + row*128 + cb);
      }
      #pragma unroll
      for (int mi = 0; mi < 4; mi++)
        #pragma unroll
        for (int ni = 0; ni < 4; ni++)
          acc[mi][ni] = MFMA(af[mi], bfr[ni], acc[mi][ni]);
    }
    __syncthreads();
  }

  #pragma unroll
  for (int mi = 0; mi < 4; mi++){
    #pragma unroll
    for (int ni = 0; ni < 4; ni++){
      int m = m0 + wr*64 + mi*16 + lg*4;
      int o = n0 + wc*64 + ni*16 + lr;
      if (EPI == 0){
        int which = o >> 9, oo = o & 511, h = oo >> 6, d = oo & 63;
        int b_ = m >> 12, n_ = m & 4095;
        if (which == 2){
          *(ushort4*)(ovt + ((((size_t)b_*8 + h)*64 + d) << 12) + n_) =
            make_ushort4(f2bf(acc[mi][ni][0]), f2bf(acc[mi][ni][1]),
                         f2bf(acc[mi][ni][2]), f2bf(acc[mi][ni][3]));
        } else {
          unsigned short* dst = (which == 0) ? oq : ok;
          size_t base = (((size_t)(b_*8 + h)) << 18) + ((size_t)n_ << 6) + d;
          #pragma unroll
          for (int r = 0; r < 4; r++)
            dst[base + (size_t)r*64] = f2bf(acc[mi][ni][r]);
        }
      } else {
        float bv = bias[o];
        #pragma unroll
        for (int r = 0; r < 4; r++)
          of[(size_t)(m + r)*512 + o] = acc[mi][ni][r] + bv;
      }
    }
  }
}

// ---------- unified attention: h0/h67 (R15-validated staged dbuf) + h1..5 ----------
__device__ __forceinline__ int map16(int win, int t){
  return (((win >> 2)*16 + (t >> 4)) << 6) + ((win & 3) << 4) + (t & 15);
}
__device__ __forceinline__ int mapw(int h, int u, int t){
  if (h <= 2) return (((u >> 2)*4 + (t >> 4)) << 6) + ((u & 3) << 4) + (t & 15);
  return (((u >> 3)*8 + (t >> 3)) << 6) + ((u & 7) << 3) + (t & 7);
}

__global__ __launch_bounds__(512)
void k_attn(const unsigned short* __restrict__ qb, const unsigned short* __restrict__ kb,
            const unsigned short* __restrict__ vtb,
            const float* __restrict__ b64, const float* __restrict__ b256,
            unsigned short* __restrict__ fsp,
            unsigned short* __restrict__ pO, float* __restrict__ pl)
{
  __shared__ unsigned short KV[2][8192];           // h0/h67: dbuf [K|V]; h15: 2 units
  __shared__ unsigned short Pp[8][2048];           // per-wave P
  const int t = threadIdx.x, l = t & 63, w = t >> 6;
  const int lr = l & 15, lg = l >> 4;
  const int v = (blockIdx.x & 7)*320 + (blockIdx.x >> 3);   // XCD-pinned, 2560 blocks
  const int b = v / 320, u = v % 320;
  const float SC = 0.125f * LOG2E;
  char* pw = (char*)Pp[w];
  bf16x8 ones8;
  #pragma unroll
  for (int e = 0; e < 8; e++) ones8[e] = (short)0x3F80;

  if (u < 160){
    // ================= h0 (KV-chunked) and h6/7 — exact R15 body =================
    int h, win, s0, s1, chunk = 0;
    const float* btab = nullptr;
    if (u < 128){ h = 0; win = u >> 3; chunk = u & 7; s0 = chunk*8; s1 = s0 + 8; }
    else { int uu = u - 128; h = 6 + (uu >> 4); win = uu & 15; s0 = 0; s1 = 4;
           btab = b256 + ((size_t)(h - 6) << 16); }
    const size_t hb = ((size_t)(b*8 + h)) << 18;

    const int srow = w*8 + (l >> 3);
    const int ssc  = (((l & 7) ^ (srow & 7)) << 3);

    bf16x8 qf[2][2];
    #pragma unroll
    for (int mf = 0; mf < 2; mf++){
      int qt = w*32 + mf*16 + lr;
      int n = (h == 0) ? (win*256 + qt) : map16(win, qt);
      const unsigned short* qp = qb + hb + ((size_t)n << 6) + lg*8;
      qf[mf][0] = *(const bf16x8*)qp;
      qf[mf][1] = *(const bf16x8*)(qp + 32);
    }
    f32x4 ao[2][4] = {};
    f32x4 lsum4[2] = {};

    auto stage = [&](int s, int buf){
      int tk = s*64 + srow;
      int nk = (h == 0) ? tk : map16(win, tk);
      gload16(kb + hb + ((size_t)nk << 6) + ssc, &KV[buf][w*512]);
      int tv = s*64 + ssc;
      int nv = (h == 0) ? tv : map16(win, tv);
      gload16(vtb + hb + ((size_t)srow << 12) + nv, &KV[buf][4096 + w*512]);
    };

    stage(s0, 0);
    asm volatile("s_waitcnt vmcnt(0)" ::: "memory");
    __builtin_amdgcn_s_barrier();

    for (int s = s0; s < s1; s++){
      const int cur = (s - s0) & 1;
      if (s + 1 < s1) stage(s + 1, cur ^ 1);
      const char* kpc = (const char*)&KV[cur][0];
      const char* vpc = (const char*)&KV[cur][4096];

      f32x4 sv[2][4] = {};
      #pragma unroll
      for (int kt = 0; kt < 2; kt++){
        bf16x8 kf[4];
        #pragma unroll
        for (int nf = 0; nf < 4; nf++){
          int row = nf*16 + lr;
          int cb  = (kt*64 + lg*16) ^ ((row & 7) << 4);
          kf[nf] = *(const bf16x8*)(kpc + row*128 + cb);
        }
        #pragma unroll
        for (int mf = 0; mf < 2; mf++)
          #pragma unroll
          for (int nf = 0; nf < 4; nf++)
            sv[mf][nf] = MFMA(qf[mf][kt], kf[nf], sv[mf][nf]);
      }
      #pragma unroll
      for (int mf = 0; mf < 2; mf++)
        #pragma unroll
        for (int nfp = 0; nfp < 2; nfp++)
          #pragma unroll
          for (int r = 0; r < 4; r++){
            int nfA = nfp*2, nfB = nfp*2 + 1;
            float xa, xb_;
            if (btab){
              int qw = w*32 + mf*16 + lg*4 + r;
              xa = __builtin_fmaf(sv[mf][nfA][r], SC, btab[(qw << 8) + s*64 + nfA*16 + lr]);
              xb_= __builtin_fmaf(sv[mf][nfB][r], SC, btab[(qw << 8) + s*64 + nfB*16 + lr]);
            } else {
              xa = sv[mf][nfA][r] * SC;
              xb_= sv[mf][nfB][r] * SC;
            }
            unsigned pk = cvt_pk_bf16(fast_exp2(xa), fast_exp2(xb_));
            int row = mf*16 + lg*4 + r;
            int swz = (row & 7) << 4;
            *(unsigned short*)(pw + row*128 + (((nfA*16 + lr)*2) ^ swz)) = (unsigned short)pk;
            *(unsigned short*)(pw + row*128 + (((nfB*16 + lr)*2) ^ swz)) = (unsigned short)(pk >> 16);
          }
      #pragma unroll
      for (int kg = 0; kg < 2; kg++){
        bf16x8 pa[2], vf[4];
        #pragma unroll
        for (int mf = 0; mf < 2; mf++){
          int row = mf*16 + lr;
          int cb  = (kg*64 + lg*16) ^ ((row & 7) << 4);
          pa[mf] = *(const bf16x8*)(pw + row*128 + cb);
        }
        #pragma unroll
        for (int df = 0; df < 4; df++){
          int row = df*16 + lr;
          int cb  = (kg*64 + lg*16) ^ ((row & 7) << 4);
          vf[df] = *(const bf16x8*)(vpc + row*128 + cb);
        }
        #pragma unroll
        for (int mf = 0; mf < 2; mf++){
          #pragma unroll
          for (int df = 0; df < 4; df++)
            ao[mf][df] = MFMA(pa[mf], vf[df], ao[mf][df]);
          lsum4[mf] = MFMA(pa[mf], ones8, lsum4[mf]);
        }
      }
      asm volatile("s_waitcnt vmcnt(0)" ::: "memory");
      __builtin_amdgcn_s_barrier();
    }

    if (h == 0){
      #pragma unroll
      for (int mf = 0; mf < 2; mf++)
        #pragma unroll
        for (int r = 0; r < 4; r++){
          int qt = w*32 + mf*16 + lg*4 + r;
          size_t rowb = (((size_t)(b*8 + chunk)) << 12) + win*256 + qt;
          if (lr == 0) pl[rowb] = lsum4[mf][r];
          #pragma unroll
          for (int df = 0; df < 4; df++)
            pO[(rowb << 6) + df*16 + lr] = f2bf(ao[mf][df][r]);
        }
    } else {
      #pragma unroll
      for (int mf = 0; mf < 2; mf++)
        #pragma unroll
        for (int df = 0; df < 4; df++)
          #pragma unroll
          for (int r = 0; r < 4; r++){
            float o = ao[mf][df][r] / lsum4[mf][r];
            int qt = w*32 + mf*16 + lg*4 + r;
            int np = win*256 + qt;
            fsp[(((size_t)b*4096 + np) << 9) + h*64 + df*16 + lr] = f2bf(o);
          }
    }
  } else {
    // ================= h1..5: 2 window-units per block, 1 step, mf=1 =================
    int j = u - 160;                 // 0..159
    int h = 1 + (j >> 5);            // 32 blocks per head
    int jj = j & 31;
    int ui = w >> 2, wi = w & 3;     // unit-in-block, wave-in-unit
    int u15 = jj*2 + ui;             // window-unit 0..63
    const size_t hb = ((size_t)(b*8 + h)) << 18;
    const float* bt = b64 + ((size_t)(h-1) << 12);
    char* base = (char*)&KV[0][0] + ui*16384;      // [K 8KB | V 8KB] per unit

    // stage both units' K and V^T (validated win64 pattern, per-wave 16 rows each)
    #pragma unroll
    for (int i = 0; i < 2; i++){
      int r = wi*16 + i*8 + (l >> 3);
      int sc = (((l & 7) ^ (r & 7)) << 3);
      gload16(kb  + hb + ((size_t)mapw(h, u15, r) << 6) + sc, base + (wi*16 + i*8)*128);
      gload16(vtb + hb + ((size_t)r << 12) + mapw(h, u15, sc), base + 8192 + (wi*16 + i*8)*128);
    }
    bf16x8 qf0, qf1;
    {
      int qt0 = wi*16 + lr;
      int nq = mapw(h, u15, qt0);
      const unsigned short* qp = qb + hb + ((size_t)nq << 6) + lg*8;
      qf0 = *(const bf16x8*)qp;
      qf1 = *(const bf16x8*)(qp + 32);
    }
    asm volatile("s_waitcnt vmcnt(0)" ::: "memory");
    __builtin_amdgcn_s_barrier();

    const char* kpc = base;
    const char* vpc = base + 8192;
    f32x4 ao4[4] = {};
    f32x4 ls = {};

    #pragma unroll
    for (int nfp = 0; nfp < 2; nfp++){
      f32x4 sv[2] = {};
      #pragma unroll
      for (int kt = 0; kt < 2; kt++)
        #pragma unroll
        for (int nfi = 0; nfi < 2; nfi++){
          int row = (nfp*2 + nfi)*16 + lr;
          int cb  = (kt*64 + lg*16) ^ ((row & 7) << 4);
          bf16x8 kf = *(const bf16x8*)(kpc + row*128 + cb);
          sv[nfi] = MFMA(kt == 0 ? qf0 : qf1, kf, sv[nfi]);
        }
      #pragma unroll
      for (int r = 0; r < 4; r++){
        int qw = wi*16 + lg*4 + r;
        float xa = __builtin_fmaf(sv[0][r], SC, bt[(qw << 6) + (nfp*2)*16 + lr]);
        float xb_= __builtin_fmaf(sv[1][r], SC, bt[(qw << 6) + (nfp*2+1)*16 + lr]);
        unsigned pk = cvt_pk_bf16(fast_exp2(xa), fast_exp2(xb_));
        int row = lg*4 + r;
        int swz = (row & 7) << 4;
        *(unsigned short*)(pw + row*128 + ((((nfp*2)*16 + lr)*2) ^ swz)) = (unsigned short)pk;
        *(unsigned short*)(pw + row*128 + ((((nfp*2+1)*16 + lr)*2) ^ swz)) = (unsigned short)(pk >> 16);
      }
    }
    #pragma unroll
    for (int kg = 0; kg < 2; kg++){
      bf16x8 pa;
      {
        int cb = (kg*64 + lg*16) ^ ((lr & 7) << 4);
        pa = *(const bf16x8*)(pw + lr*128 + cb);
      }
      #pragma unroll
      for (int df = 0; df < 4; df++){
        int row = df*16 + lr;
        int cb  = (kg*64 + lg*16) ^ ((row & 7) << 4);
        bf16x8 vf = *(const bf16x8*)(vpc + row*128 + cb);
        ao4[df] = MFMA(pa, vf, ao4[df]);
      }
      ls = MFMA(pa, ones8, ls);
    }
    #pragma unroll
    for (int df = 0; df < 4; df++)
      #pragma unroll
      for (int r = 0; r < 4; r++){
        float o = ao4[df][r] / ls[r];
        int qt = wi*16 + lg*4 + r;             // unit-local token
        int np;
        if (h <= 2){
          int r4 = qt >> 4, w_ = (qt >> 2) & 3, c = qt & 3;
          np = (u15 >> 2)*256 + (u15 & 3)*64 + w_*16 + r4*4 + c;
        } else {
          np = u15*64 + qt;
        }
        fsp[(((size_t)b*4096 + np) << 9) + h*64 + df*16 + lr] = f2bf(o);
      }
  }
}

// ---------- combine head-0 KV chunks (plain sums) ----------
__global__ __launch_bounds__(256)
void k_comb(const unsigned short* __restrict__ pO, const float* __restrict__ pl,
            unsigned short* __restrict__ fsp){
  int tid = blockIdx.x*256 + threadIdx.x;      // 2M = 32768 rows * 64 d
  int d = tid & 63;
  int row = tid >> 6;
  int b = row >> 12;
  int n = row & 4095;
  float o = 0.f, L = 0.f;
  #pragma unroll
  for (int c = 0; c < 8; c++){
    size_t rr = (((size_t)(b*8 + c)) << 12) + n;
    L += pl[rr];
    o += bf2f(pO[(rr << 6) + d]);
  }
  o /= L;
  fsp[(((size_t)b*4096 + n) << 9) + d] = f2bf(o);
}

// ---------- launch ----------
extern "C" void kernel_launch(void* const* d_in, const int* in_sizes, int n_in,
                              void* d_out, int out_size, void* d_ws, size_t ws_size,
                              hipStream_t stream) {
  const float* x     = (const float*)d_in[0];
  const float* Wq    = (const float*)d_in[1];
  const float* Wkv   = (const float*)d_in[2];
  const float* Wp    = (const float*)d_in[3];
  const float* bproj = (const float*)d_in[4];
  const float* t1 = (const float*)d_in[7];
  const float* t2 = (const float*)d_in[8];
  const float* t3 = (const float*)d_in[9];
  const float* t4 = (const float*)d_in[10];
  const float* t5 = (const float*)d_in[11];
  const float* t6 = (const float*)d_in[12];
  const float* t7 = (const float*)d_in[13];

  char* W = (char*)d_ws;
  size_t off = 0;
  auto alloc = [&](size_t bytes)->char*{
    char* p = W + off; off += (bytes + 255) & ~(size_t)255; return p;
  };
  unsigned short* xb   = (unsigned short*)alloc((size_t)32768*512*2);   // dead after gemm0
  unsigned short* wqkv = (unsigned short*)alloc((size_t)1536*512*2);    // dead after gemm0
  unsigned short* wsp  = (unsigned short*)alloc((size_t)512*512*2);
  unsigned short* qbuf = (unsigned short*)alloc((size_t)8*8*4096*64*2);
  unsigned short* kbuf = (unsigned short*)alloc((size_t)8*8*4096*64*2);
  unsigned short* vtb  = (unsigned short*)alloc((size_t)8*8*4096*64*2);
  unsigned short* fsp  = (unsigned short*)alloc((size_t)32768*512*2);
  float* b64  = (float*)alloc((size_t)5*64*64*4);
  float* b256 = (float*)alloc((size_t)2*256*256*4);
  if (off > ws_size) return;

  // head-0 partials alias dead regions (attn runs after gemm0):
  unsigned short* pO = xb;                 // (8b*8c)*4096 rows * 64 d * 2B = 32 MiB
  float* pl = (float*)wqkv;                // 64*4096*4B = 1 MiB

  k_prep<<<8192, 256, 0, stream>>>(x, xb, Wq, Wkv, Wp, t1,t2,t3,t4,t5,t6,t7,
                                   wqkv, wsp, b64, b256);
  k_gemm<0><<<3072, 256, 0, stream>>>(xb, wqkv, 32768,
                                      qbuf, kbuf, vtb, nullptr, nullptr);
  k_attn<<<2560, 512, 0, stream>>>(qbuf, kbuf, vtb, b64, b256, fsp, pO, pl);
  k_comb<<<8192, 256, 0, stream>>>(pO, pl, fsp);
  k_gemm<1><<<1024, 256, 0, stream>>>(fsp, wsp, 32768,
                                      nullptr, nullptr, nullptr, (float*)d_out, bproj);
}